// Round 9
// baseline (117.383 us; speedup 1.0000x reference)
//
#include <hip/hip_runtime.h>
#include <stdint.h>
#include <math.h>

// Problem constants
#define BATCH 4096
#define NT    8192          // 2*BATCH
#define FD    256           // feature dim
#define TILE  128           // block tile (square)
#define BK    32            // K chunk per step (8 steps, per-wave double-buffer)
#define NUMK  5
#define NTRI  2080          // 64*65/2 triangle tiles; %8==0
#define PBLK  1024          // prep blocks (8 rows each)

typedef __attribute__((ext_vector_type(8))) short bf16x8;  // 8 bf16 = 4 VGPRs
typedef __attribute__((ext_vector_type(4))) float f32x4;

// ---- workspace layout (bytes) ----
// fb 4 MiB | sq 32 KiB | pcol 1 MiB | wsum 4 KiB | gamma 4 B
static const size_t WS_FB    = 0;
static const size_t WS_SQ    = (size_t)NT * FD * 2;              // 4194304
static const size_t WS_PCOL  = WS_SQ + (size_t)NT * 4;           // +32768
static const size_t WS_WSUM  = WS_PCOL + (size_t)PBLK * 256 * 4; // +1 MiB
static const size_t WS_GAMMA = WS_WSUM + (size_t)PBLK * 4;       // +4 KiB

__device__ __forceinline__ unsigned short f2bf_rne(float x) {
    unsigned u = __float_as_uint(x);
    unsigned r = (u + 0x7fffu + ((u >> 16) & 1u)) >> 16;
    return (unsigned short)r;
}

__device__ __forceinline__ void async_copy16(void* lds, const void* g) {
    __builtin_amdgcn_global_load_lds(
        (__attribute__((address_space(1))) void*)(void*)(const_cast<void*>(g)),
        (__attribute__((address_space(3))) void*)lds, 16, 0, 0);
}

// ---------------- kernel 1: convert + row norms + per-block partials ----------
__global__ void mmd_prep(const float* __restrict__ s_feat,
                         const float* __restrict__ t_feat,
                         unsigned short* __restrict__ fb,
                         float* __restrict__ sq,
                         float* __restrict__ pcol,
                         float* __restrict__ wsum) {
    __shared__ float cp[4][FD];
    __shared__ float rw[4];
    const int w    = threadIdx.x >> 6;
    const int lane = threadIdx.x & 63;
    float c0 = 0.f, c1 = 0.f, c2 = 0.f, c3 = 0.f;
    float wtot = 0.f;
#pragma unroll
    for (int t = 0; t < 2; ++t) {
        int row = blockIdx.x * 8 + w * 2 + t;
        const float* src = (row < BATCH) ? (s_feat + (size_t)row * FD)
                                         : (t_feat + (size_t)(row - BATCH) * FD);
        float4 v = ((const float4*)src)[lane];
        unsigned int u01 = (unsigned)f2bf_rne(v.x) | ((unsigned)f2bf_rne(v.y) << 16);
        unsigned int u23 = (unsigned)f2bf_rne(v.z) | ((unsigned)f2bf_rne(v.w) << 16);
        ((uint2*)(fb + (size_t)row * FD))[lane] = make_uint2(u01, u23);
        float ss = v.x * v.x + v.y * v.y + v.z * v.z + v.w * v.w;
        for (int off = 32; off; off >>= 1) ss += __shfl_down(ss, off);
        if (lane == 0) { sq[row] = ss; wtot += ss; }
        c0 += v.x; c1 += v.y; c2 += v.z; c3 += v.w;
    }
    cp[w][4 * lane + 0] = c0;
    cp[w][4 * lane + 1] = c1;
    cp[w][4 * lane + 2] = c2;
    cp[w][4 * lane + 3] = c3;
    if (lane == 0) rw[w] = wtot;
    __syncthreads();
    int t = threadIdx.x;
    pcol[(size_t)blockIdx.x * 256 + t] = cp[0][t] + cp[1][t] + cp[2][t] + cp[3][t];
    if (t == 0) wsum[blockIdx.x] = rw[0] + rw[1] + rw[2] + rw[3];
}

// ---------------- kernel 2: reduce partials -> gamma0; zero out ----------------
__global__ void mmd_gamma(const float* __restrict__ pcol,
                          const float* __restrict__ wsum,
                          float* __restrict__ gamma,
                          float* __restrict__ out) {
    __shared__ float gcol[4][256];
    __shared__ float redc[4], redw[16];
    const int tid  = threadIdx.x;        // 1024 threads
    const int c    = tid & 255, s = tid >> 8;
    const int lane = tid & 63;
    float a0 = 0.f, a1 = 0.f, a2 = 0.f, a3 = 0.f;
#pragma unroll 4
    for (int k = 0; k < 256; k += 4) {
        a0 += pcol[(size_t)(s * 256 + k + 0) * 256 + c];
        a1 += pcol[(size_t)(s * 256 + k + 1) * 256 + c];
        a2 += pcol[(size_t)(s * 256 + k + 2) * 256 + c];
        a3 += pcol[(size_t)(s * 256 + k + 3) * 256 + c];
    }
    gcol[s][c] = (a0 + a1) + (a2 + a3);
    float wv = wsum[tid];
    for (int off = 32; off; off >>= 1) wv += __shfl_down(wv, off);
    if (lane == 0) redw[tid >> 6] = wv;
    __syncthreads();
    if (tid < 256) {
        float colv = gcol[0][c] + gcol[1][c] + gcol[2][c] + gcol[3][c];
        float cv2 = colv * colv;
        for (int off = 32; off; off >>= 1) cv2 += __shfl_down(cv2, off);
        if (lane == 0) redc[tid >> 6] = cv2;
    }
    __syncthreads();
    if (tid == 0) {
        float s2 = (redc[0] + redc[1]) + (redc[2] + redc[3]);
        float ssq = 0.f;
#pragma unroll
        for (int i = 0; i < 16; ++i) ssq += redw[i];
        float sumd = 2.0f * (float)NT * ssq - 2.0f * s2;
        float n2n  = (float)((long long)NT * NT - NT);   // n^2 - n
        gamma[0]   = 0.25f * (n2n / sumd);   // bw / 2^(NUM_KERNELS//2)
        out[0]     = 0.f;
    }
}

// ---------------- kernel 3: fused GEMM + gaussian-kernel + reduce ----------------
// ZERO-BARRIER K-loop: each of the 4 waves owns a 64x64 output sub-tile and a
// PRIVATE 16 KiB double-buffered LDS stage (A 4K + B 4K per buffer). vmcnt /
// lgkmcnt are per-wave, so waves free-run and their VALU / ds_read / MFMA /
// DMA phases interleave across the 8 resident waves per CU (breaks the
// barrier-convoy phase serialization seen in rounds 0-8).
__global__ __launch_bounds__(256, 2) void mmd_main(
    const unsigned short* __restrict__ fb,
    const float* __restrict__ sq,
    const float* __restrict__ gamma,
    float* __restrict__ out) {
    // XCD-chunked swizzle (NTRI % 8 == 0 -> bijective)
    const int bid = blockIdx.x;
    const int swz = (bid & 7) * (NTRI / 8) + (bid >> 3);
    // decode linear triangle index -> (bi <= bj)
    int r = (int)((sqrtf(8.0f * (float)swz + 1.0f) - 1.0f) * 0.5f);
    while ((r + 1) * (r + 2) / 2 <= swz) ++r;
    while (r * (r + 1) / 2 > swz) --r;
    const int bi = swz - r * (r + 1) / 2;   // 0..r
    const int bj = r;

    // wave-private staging: [wave][buf][64 rows x 32 k]
    __shared__ __align__(16) unsigned short a_t[4][2][64 * BK];  // 32 KiB
    __shared__ __align__(16) unsigned short b_t[4][2][64 * BK];  // 32 KiB
    __shared__ float sqa[TILE], sqb[TILE];
    __shared__ float red[4];

    const int tid  = threadIdx.x;
    const int w    = tid >> 6, lane = tid & 63;
    const int wm   = w >> 1, wn = w & 1;         // 2x2 waves over 128x128
    const int quad = lane >> 4, m16 = lane & 15;
    const int lrow16 = lane >> 2;                // 0..15 row within 16-row group
    const int pslot  = lane & 3;                 // physical 16B slot within 64B row

    const size_t rowA0 = (size_t)bi * TILE + wm * 64;   // this wave's A rows
    const size_t rowB0 = (size_t)bj * TILE + wn * 64;   // this wave's B rows

    // oldest loads first
    float sqv = 0.f;
    if (tid < TILE) sqv = sq[(size_t)bi * TILE + tid];
    else            sqv = sq[(size_t)bj * TILE + (tid - TILE)];
    const float g0 = gamma[0];

    // Swizzle: physical slot p of row rr holds global chunk p ^ ((rr>>1)&3).
#define STAGE_W(buf, k0_) do {                                                 \
        _Pragma("unroll")                                                      \
        for (int q = 0; q < 4; ++q) {                                          \
            int rr_ = q * 16 + lrow16;            /* local row 0..63 */        \
            int gc_ = pslot ^ ((rr_ >> 1) & 3);                                \
            async_copy16(&a_t[w][buf][(q * 16) * BK],                          \
                         fb + (rowA0 + rr_) * FD + (k0_) + gc_ * 8);           \
        }                                                                      \
        _Pragma("unroll")                                                      \
        for (int q = 0; q < 4; ++q) {                                          \
            int rr_ = q * 16 + lrow16;                                         \
            int gc_ = pslot ^ ((rr_ >> 1) & 3);                                \
            async_copy16(&b_t[w][buf][(q * 16) * BK],                          \
                         fb + (rowB0 + rr_) * FD + (k0_) + gc_ * 8);           \
        }                                                                      \
    } while (0)

    STAGE_W(0, 0);          // 8 loads
    STAGE_W(1, BK);         // 8 loads  (16 outstanding)

    if (tid < TILE) sqa[tid] = sqv;
    else            sqb[tid - TILE] = sqv;

    const f32x4 fzero = {0.f, 0.f, 0.f, 0.f};
    f32x4 acc[4][4];
#pragma unroll
    for (int a = 0; a < 4; ++a)
#pragma unroll
        for (int b = 0; b < 4; ++b) acc[a][b] = fzero;

    // -------- barrier-free K-loop (per-wave counted waits only) --------
#pragma unroll
    for (int st = 0; st < 8; ++st) {
        const int cur = st & 1;   // compile-time after full unroll
        // certify buf[cur]: drain its 8 loads, keep the next buffer's 8 in
        // flight (per-wave counter; no cross-wave sync needed).
        if (st == 7) asm volatile("s_waitcnt vmcnt(0)" ::: "memory");
        else         asm volatile("s_waitcnt vmcnt(8)" ::: "memory");
        __builtin_amdgcn_sched_barrier(0);

        bf16x8 af[4], bf[4];
#pragma unroll
        for (int tm = 0; tm < 4; ++tm) {
            int ra = tm * 16 + m16;                  // local row 0..63
            int p = quad ^ ((ra >> 1) & 3);
            af[tm] = *(const bf16x8*)&a_t[w][cur][ra * BK + p * 8];
        }
#pragma unroll
        for (int tn = 0; tn < 4; ++tn) {
            int rb = tn * 16 + m16;
            int p = quad ^ ((rb >> 1) & 3);
            bf[tn] = *(const bf16x8*)&b_t[w][cur][rb * BK + p * 8];
        }
        // frags delivered -> safe to overwrite buf[cur] with chunk st+2
        asm volatile("s_waitcnt lgkmcnt(0)" ::: "memory");
        __builtin_amdgcn_sched_barrier(0);   // rule 18: MFMA must not hoist
        if (st < 6) STAGE_W(cur, (st + 2) * BK);
        __builtin_amdgcn_sched_barrier(0);   // keep STAGE issued before MFMAs

        __builtin_amdgcn_s_setprio(1);
#pragma unroll
        for (int tm = 0; tm < 4; ++tm)
#pragma unroll
            for (int tn = 0; tn < 4; ++tn)
                acc[tm][tn] = __builtin_amdgcn_mfma_f32_16x16x32_bf16(
                    af[tm], bf[tn], acc[tm][tn], 0, 0, 0);
        __builtin_amdgcn_s_setprio(0);
    }

    __syncthreads();   // only block-wide sync: sqa/sqb visible for epilogue

    // ---- epilogue: d = sq_i + sq_j - 2 dot, clamp, e + e^2 + e^4 + e^8 + e^16 ----
    float ls[4] = {0.f, 0.f, 0.f, 0.f};
#pragma unroll
    for (int tm = 0; tm < 4; ++tm) {
        const int i0 = wm * 64 + tm * 16 + quad * 4;
        float sqi[4] = {sqa[i0 + 0], sqa[i0 + 1], sqa[i0 + 2], sqa[i0 + 3]};
#pragma unroll
        for (int tn = 0; tn < 4; ++tn) {
            const int j = wn * 64 + tn * 16 + m16;
            const float sqj = sqb[j];
#pragma unroll
            for (int rr = 0; rr < 4; ++rr) {
                float d = fmaf(-2.f, acc[tm][tn][rr], sqi[rr] + sqj);
                d = fmaxf(d, 0.f);
                float e1 = __expf(-d * g0);
                float e2 = e1 * e1, e4 = e2 * e2, e8 = e4 * e4, e16 = e8 * e8;
                ls[rr] += e1 + e2 + e4 + e8 + e16;
            }
        }
    }
    float lsum = (ls[0] + ls[1]) + (ls[2] + ls[3]);
    for (int off = 32; off; off >>= 1) lsum += __shfl_down(lsum, off);
    if (lane == 0) red[w] = lsum;
    __syncthreads();
    if (tid == 0) {
        float wgt;
        if (bi == bj) wgt = 1.f;                                  // diagonal tile, once
        else wgt = ((bi < 32) == (bj < 32)) ? 2.f : -2.f;         // mirrored tile folded in
        float scale = wgt * (1.f / NUMK) * (1.f / 16777216.f);    // /(NUMK*4096^2)
        atomicAdd(out, (red[0] + red[1] + red[2] + red[3]) * scale);
    }
}

extern "C" void kernel_launch(void* const* d_in, const int* in_sizes, int n_in,
                              void* d_out, int out_size, void* d_ws, size_t ws_size,
                              hipStream_t stream) {
    const float* s_feat = (const float*)d_in[0];
    const float* t_feat = (const float*)d_in[1];
    char* ws = (char*)d_ws;
    unsigned short* fb = (unsigned short*)(ws + WS_FB);
    float* sq    = (float*)(ws + WS_SQ);
    float* pcol  = (float*)(ws + WS_PCOL);
    float* wsum  = (float*)(ws + WS_WSUM);
    float* gamma = (float*)(ws + WS_GAMMA);
    float* out   = (float*)d_out;

    mmd_prep<<<PBLK, 256, 0, stream>>>(s_feat, t_feat, fb, sq, pcol, wsum);
    mmd_gamma<<<1, 1024, 0, stream>>>(pcol, wsum, gamma, out);
    mmd_main<<<NTRI, 256, 0, stream>>>(fb, sq, gamma, out);
}